// Round 1
// baseline (371.836 us; speedup 1.0000x reference)
//
#include <hip/hip_runtime.h>
#include <stdint.h>

// ---------------------------------------------------------------------------
// GCN 2-layer encoder:
//   h1 = x @ W1 ; g1 = relu(Agg(h1) + b1) ; h2 = g1 @ W2 ; out = Agg(h2) + b2
// Agg = symmetric-normalized adjacency with self loops, built as dest-CSR.
// ---------------------------------------------------------------------------

__global__ void k_init(uint32_t* __restrict__ cnt, uint32_t* __restrict__ fill, int n) {
    int i = blockIdx.x * blockDim.x + threadIdx.x;
    if (i < n) { cnt[i] = 1u; fill[i] = 0u; }   // cnt starts at 1 (self loop)
}

__global__ void k_count(const int* __restrict__ col, uint32_t* __restrict__ cnt, int E) {
    int i = blockIdx.x * blockDim.x + threadIdx.x;
    if (i < E) atomicAdd(&cnt[col[i]], 1u);
}

__global__ void k_dinv(const uint32_t* __restrict__ cnt, float* __restrict__ dinv, int n) {
    int i = blockIdx.x * blockDim.x + threadIdx.x;
    if (i < n) dinv[i] = rsqrtf((float)cnt[i]);  // cnt >= 1 always
}

// ---- exclusive scan of cnt -> rp (row_ptr), 3 kernels ----
constexpr int SCAN_CH = 512;

__global__ void k_scan_partial(const uint32_t* __restrict__ cnt, uint32_t* __restrict__ part, int n) {
    __shared__ uint32_t s[256];
    int t = threadIdx.x;
    int base = blockIdx.x * SCAN_CH;
    uint32_t v = 0;
    if (base + t       < n) v += cnt[base + t];
    if (base + t + 256 < n) v += cnt[base + t + 256];
    s[t] = v; __syncthreads();
    for (int off = 128; off > 0; off >>= 1) {
        if (t < off) s[t] += s[t + off];
        __syncthreads();
    }
    if (t == 0) part[blockIdx.x] = s[0];
}

__global__ void k_scan_top(uint32_t* __restrict__ part, uint32_t* __restrict__ total_out, int nb) {
    uint32_t run = 0;
    for (int b = 0; b < nb; ++b) { uint32_t t = part[b]; part[b] = run; run += t; }
    *total_out = run;   // rp[n] = E + n
}

__global__ void k_scan_final(const uint32_t* __restrict__ cnt, const uint32_t* __restrict__ part,
                             uint32_t* __restrict__ rp, int n) {
    __shared__ uint32_t s[SCAN_CH];
    int t = threadIdx.x;
    int i = blockIdx.x * SCAN_CH + t;
    uint32_t v = (i < n) ? cnt[i] : 0u;
    s[t] = v; __syncthreads();
    for (int off = 1; off < SCAN_CH; off <<= 1) {
        uint32_t u = (t >= off) ? s[t - off] : 0u;
        __syncthreads();
        s[t] += u;
        __syncthreads();
    }
    if (i < n) rp[i] = part[blockIdx.x] + s[t] - v;   // exclusive
}

// bucket-scatter edges (+ self loops) into dest-CSR order
__global__ void k_scatter(const int* __restrict__ row, const int* __restrict__ col,
                          const float* __restrict__ dinv,
                          const uint32_t* __restrict__ rp, uint32_t* __restrict__ fill,
                          int* __restrict__ esrc, float* __restrict__ enorm, int E, int n) {
    int i = blockIdx.x * blockDim.x + threadIdx.x;
    int M = E + n;
    if (i >= M) return;
    int r, c;
    if (i < E) { r = row[i]; c = col[i]; }
    else       { r = c = i - E; }
    uint32_t p = rp[c] + atomicAdd(&fill[c], 1u);
    esrc[p]  = r;
    enorm[p] = dinv[r] * dinv[c];
}

// ---- GEMM: H[n,FOUT] = X[n,128] @ W[128,FOUT], fp32, W staged in LDS ----
template <int FOUT>
__global__ __launch_bounds__((FOUT / 4) * 8)
void k_gemm(const float* __restrict__ X, const float* __restrict__ W,
            float* __restrict__ H, int n) {
    constexpr int K = 128;
    __shared__ float Wl[K * FOUT];
    const int tx = threadIdx.x;                 // 0..FOUT/4-1 (col quad)
    const int ty = threadIdx.y;                 // 0..7
    const int nthr = (FOUT / 4) * 8;
    const int tid = ty * (FOUT / 4) + tx;
    for (int i = tid; i < K * FOUT / 4; i += nthr)
        reinterpret_cast<float4*>(Wl)[i] = reinterpret_cast<const float4*>(W)[i];
    __syncthreads();

    const int row0 = blockIdx.x * 64;
    float4 acc[8];
#pragma unroll
    for (int r = 0; r < 8; ++r) acc[r] = make_float4(0.f, 0.f, 0.f, 0.f);

#pragma unroll 2
    for (int k0 = 0; k0 < K; k0 += 4) {
        const float4 w0 = *reinterpret_cast<const float4*>(&Wl[(k0 + 0) * FOUT + tx * 4]);
        const float4 w1 = *reinterpret_cast<const float4*>(&Wl[(k0 + 1) * FOUT + tx * 4]);
        const float4 w2 = *reinterpret_cast<const float4*>(&Wl[(k0 + 2) * FOUT + tx * 4]);
        const float4 w3 = *reinterpret_cast<const float4*>(&Wl[(k0 + 3) * FOUT + tx * 4]);
#pragma unroll
        for (int r = 0; r < 8; ++r) {
            int rw = row0 + r * 8 + ty;
            int rl = rw < n ? rw : n - 1;       // clamp (store is guarded)
            float4 xv = *reinterpret_cast<const float4*>(&X[(size_t)rl * K + k0]);
            acc[r].x += xv.x * w0.x + xv.y * w1.x + xv.z * w2.x + xv.w * w3.x;
            acc[r].y += xv.x * w0.y + xv.y * w1.y + xv.z * w2.y + xv.w * w3.y;
            acc[r].z += xv.x * w0.z + xv.y * w1.z + xv.z * w2.z + xv.w * w3.z;
            acc[r].w += xv.x * w0.w + xv.y * w1.w + xv.z * w2.w + xv.w * w3.w;
        }
    }
#pragma unroll
    for (int r = 0; r < 8; ++r) {
        int rw = row0 + r * 8 + ty;
        if (rw < n)
            *reinterpret_cast<float4*>(&H[(size_t)rw * FOUT + tx * 4]) = acc[r];
    }
}

// ---- pull aggregation: out[v] = sum_e norm[e]*H[src[e]] + bias (opt relu) ----
template <int F, bool RELU>
__global__ void k_agg(const float* __restrict__ H, const uint32_t* __restrict__ rp,
                      const int* __restrict__ esrc, const float* __restrict__ enorm,
                      const float* __restrict__ bias, float* __restrict__ out, int n) {
    int wave = (blockIdx.x * blockDim.x + threadIdx.x) >> 6;
    int lane = threadIdx.x & 63;
    if (wave >= n) return;
    const int v = wave;
    int p = (int)rp[v];
    const int e = (int)rp[v + 1];

    if (F == 128) {
        const int c0 = lane * 2;
        float ax = 0.f, ay = 0.f;
        for (; p + 1 < e; p += 2) {
            int   s0 = esrc[p],   s1 = esrc[p + 1];
            float n0 = enorm[p],  n1 = enorm[p + 1];
            float2 h0 = *reinterpret_cast<const float2*>(&H[(size_t)s0 * 128 + c0]);
            float2 h1 = *reinterpret_cast<const float2*>(&H[(size_t)s1 * 128 + c0]);
            ax += n0 * h0.x + n1 * h1.x;
            ay += n0 * h0.y + n1 * h1.y;
        }
        if (p < e) {
            int s0 = esrc[p]; float n0 = enorm[p];
            float2 h0 = *reinterpret_cast<const float2*>(&H[(size_t)s0 * 128 + c0]);
            ax += n0 * h0.x;
            ay += n0 * h0.y;
        }
        ax += bias[c0]; ay += bias[c0 + 1];
        if (RELU) { ax = fmaxf(ax, 0.f); ay = fmaxf(ay, 0.f); }
        *reinterpret_cast<float2*>(&out[(size_t)v * 128 + c0]) = make_float2(ax, ay);
    } else {  // F == 64
        float a = 0.f;
        for (; p + 1 < e; p += 2) {
            int   s0 = esrc[p],  s1 = esrc[p + 1];
            float n0 = enorm[p], n1 = enorm[p + 1];
            a += n0 * H[(size_t)s0 * F + lane] + n1 * H[(size_t)s1 * F + lane];
        }
        if (p < e) a += enorm[p] * H[(size_t)esrc[p] * F + lane];
        a += bias[lane];
        if (RELU) a = fmaxf(a, 0.f);
        out[(size_t)v * F + lane] = a;
    }
}

extern "C" void kernel_launch(void* const* d_in, const int* in_sizes, int n_in,
                              void* d_out, int out_size, void* d_ws, size_t ws_size,
                              hipStream_t stream) {
    const float* x  = (const float*)d_in[0];
    const int*   ei = (const int*)d_in[1];
    const float* W1 = (const float*)d_in[2];
    const float* b1 = (const float*)d_in[3];
    const float* W2 = (const float*)d_in[4];
    const float* b2 = (const float*)d_in[5];
    float* out = (float*)d_out;

    const int hidden = in_sizes[3];                 // 128
    const int fout   = in_sizes[5];                 // 64
    const int fin    = in_sizes[2] / hidden;        // 128
    const int n      = in_sizes[0] / fin;           // 50000
    const int E      = in_sizes[1] / 2;             // 800000
    const int M      = E + n;
    const int* rowi = ei;                           // edge_index[0] = sources
    const int* coli = ei + E;                       // edge_index[1] = targets
    (void)fout; (void)n_in; (void)out_size; (void)ws_size;

    char* ws = (char*)d_ws;
    size_t off = 0;
    auto alloc = [&](size_t bytes) -> void* {
        off = (off + 255) & ~(size_t)255;
        void* p = ws + off;
        off += bytes;
        return p;
    };
    uint32_t* cnt   = (uint32_t*)alloc((size_t)n * 4);
    uint32_t* fill  = (uint32_t*)alloc((size_t)n * 4);
    float*    dinv  = (float*)   alloc((size_t)n * 4);
    uint32_t* rp    = (uint32_t*)alloc((size_t)(n + 1) * 4);
    uint32_t* part  = (uint32_t*)alloc(1024);
    int*      esrc  = (int*)     alloc((size_t)M * 4);
    float*    enorm = (float*)   alloc((size_t)M * 4);
    float*    h1    = (float*)   alloc((size_t)n * 128 * 4);  // also reused for h2
    float*    g1    = (float*)   alloc((size_t)n * 128 * 4);
    float*    h2    = h1;

    const int nb256 = (n + 255) / 256;
    const int nbs   = (n + SCAN_CH - 1) / SCAN_CH;

    k_init <<<nb256, 256, 0, stream>>>(cnt, fill, n);
    k_count<<<(E + 255) / 256, 256, 0, stream>>>(coli, cnt, E);
    k_dinv <<<nb256, 256, 0, stream>>>(cnt, dinv, n);
    k_scan_partial<<<nbs, 256, 0, stream>>>(cnt, part, n);
    k_scan_top    <<<1, 1, 0, stream>>>(part, rp + n, nbs);
    k_scan_final  <<<nbs, SCAN_CH, 0, stream>>>(cnt, part, rp, n);
    k_scatter<<<(M + 255) / 256, 256, 0, stream>>>(rowi, coli, dinv, rp, fill, esrc, enorm, E, n);

    const int gb = (n + 63) / 64;
    k_gemm<128><<<gb, dim3(32, 8), 0, stream>>>(x, W1, h1, n);
    k_agg<128, true><<<(n + 3) / 4, 256, 0, stream>>>(h1, rp, esrc, enorm, b1, g1, n);
    k_gemm<64><<<gb, dim3(16, 8), 0, stream>>>(g1, W2, h2, n);
    k_agg<64, false><<<(n + 3) / 4, 256, 0, stream>>>(h2, rp, esrc, enorm, b2, out, n);
}

// Round 2
// 336.254 us; speedup vs baseline: 1.1058x; 1.1058x over previous
//
#include <hip/hip_runtime.h>
#include <stdint.h>

// ---------------------------------------------------------------------------
// GCN 2-layer encoder, dest-CSR pull aggregation, fp16 intermediates.
//   h1 = fp16(x @ W1) ; g1 = relu(Agg(h1) + b1)  [fp32]
//   h2 = fp16(g1 @ W2); out = Agg(h2) + b2       [fp32]
// ---------------------------------------------------------------------------

typedef _Float16 h2v __attribute__((ext_vector_type(2)));
typedef _Float16 h4v __attribute__((ext_vector_type(4)));

__global__ void k_init(uint32_t* __restrict__ cnt, uint32_t* __restrict__ fill, int n) {
    int i = blockIdx.x * blockDim.x + threadIdx.x;
    if (i < n) { cnt[i] = 1u; fill[i] = 0u; }   // cnt starts at 1 (self loop)
}

__global__ void k_count(const int* __restrict__ col, uint32_t* __restrict__ cnt, int E) {
    int i = blockIdx.x * blockDim.x + threadIdx.x;
    if (i < E) atomicAdd(&cnt[col[i]], 1u);
}

// ---- exclusive scan of cnt -> rp (row_ptr) ----
constexpr int SCAN_CH = 512;

__global__ void k_scan_partial(const uint32_t* __restrict__ cnt, uint32_t* __restrict__ part, int n) {
    __shared__ uint32_t s[256];
    int t = threadIdx.x;
    int base = blockIdx.x * SCAN_CH;
    uint32_t v = 0;
    if (base + t       < n) v += cnt[base + t];
    if (base + t + 256 < n) v += cnt[base + t + 256];
    s[t] = v; __syncthreads();
    for (int off = 128; off > 0; off >>= 1) {
        if (t < off) s[t] += s[t + off];
        __syncthreads();
    }
    if (t == 0) part[blockIdx.x] = s[0];
}

// parallel top-level scan over <=256 partials (nb = ceil(50000/512) = 98)
__global__ void k_scan_top(uint32_t* __restrict__ part, uint32_t* __restrict__ total_out, int nb) {
    __shared__ uint32_t s[256];
    int t = threadIdx.x;
    uint32_t v = (t < nb) ? part[t] : 0u;
    s[t] = v; __syncthreads();
    for (int off = 1; off < 256; off <<= 1) {
        uint32_t u = (t >= off) ? s[t - off] : 0u;
        __syncthreads();
        s[t] += u;
        __syncthreads();
    }
    if (t < nb) part[t] = s[t] - v;          // exclusive
    if (t == nb - 1) *total_out = s[t];      // rp[n] = E + n
}

__global__ void k_scan_final(const uint32_t* __restrict__ cnt, const uint32_t* __restrict__ part,
                             uint32_t* __restrict__ rp, int n) {
    __shared__ uint32_t s[SCAN_CH];
    int t = threadIdx.x;
    int i = blockIdx.x * SCAN_CH + t;
    uint32_t v = (i < n) ? cnt[i] : 0u;
    s[t] = v; __syncthreads();
    for (int off = 1; off < SCAN_CH; off <<= 1) {
        uint32_t u = (t >= off) ? s[t - off] : 0u;
        __syncthreads();
        s[t] += u;
        __syncthreads();
    }
    if (i < n) rp[i] = part[blockIdx.x] + s[t] - v;   // exclusive
}

// bucket-scatter edges (+ self loops) into dest-CSR order; interleaved {src, norm}
__global__ void k_scatter(const int* __restrict__ row, const int* __restrict__ col,
                          const uint32_t* __restrict__ cnt,
                          const uint32_t* __restrict__ rp, uint32_t* __restrict__ fill,
                          int2* __restrict__ ed, int E, int n) {
    int i = blockIdx.x * blockDim.x + threadIdx.x;
    int M = E + n;
    if (i >= M) return;
    int r, c;
    if (i < E) { r = row[i]; c = col[i]; }
    else       { r = c = i - E; }
    uint32_t p = rp[c] + atomicAdd(&fill[c], 1u);
    float nrm = rsqrtf((float)cnt[r] * (float)cnt[c]);
    ed[p] = make_int2(r, __float_as_int(nrm));
}

// ---- GEMM: H[n,FOUT](fp16) = X[n,128](fp32) @ W[128,FOUT](fp32) ----
template <int FOUT>
__global__ __launch_bounds__((FOUT / 4) * 8)
void k_gemm(const float* __restrict__ X, const float* __restrict__ W,
            _Float16* __restrict__ H, int n) {
    constexpr int K = 128;
    __shared__ float Wl[K * FOUT];
    const int tx = threadIdx.x;                 // 0..FOUT/4-1 (col quad)
    const int ty = threadIdx.y;                 // 0..7
    const int nthr = (FOUT / 4) * 8;
    const int tid = ty * (FOUT / 4) + tx;
    for (int i = tid; i < K * FOUT / 4; i += nthr)
        reinterpret_cast<float4*>(Wl)[i] = reinterpret_cast<const float4*>(W)[i];
    __syncthreads();

    const int row0 = blockIdx.x * 64;
    float4 acc[8];
#pragma unroll
    for (int r = 0; r < 8; ++r) acc[r] = make_float4(0.f, 0.f, 0.f, 0.f);

#pragma unroll 2
    for (int k0 = 0; k0 < K; k0 += 4) {
        const float4 w0 = *reinterpret_cast<const float4*>(&Wl[(k0 + 0) * FOUT + tx * 4]);
        const float4 w1 = *reinterpret_cast<const float4*>(&Wl[(k0 + 1) * FOUT + tx * 4]);
        const float4 w2 = *reinterpret_cast<const float4*>(&Wl[(k0 + 2) * FOUT + tx * 4]);
        const float4 w3 = *reinterpret_cast<const float4*>(&Wl[(k0 + 3) * FOUT + tx * 4]);
#pragma unroll
        for (int r = 0; r < 8; ++r) {
            int rw = row0 + r * 8 + ty;
            int rl = rw < n ? rw : n - 1;       // clamp (store is guarded)
            float4 xv = *reinterpret_cast<const float4*>(&X[(size_t)rl * K + k0]);
            acc[r].x += xv.x * w0.x + xv.y * w1.x + xv.z * w2.x + xv.w * w3.x;
            acc[r].y += xv.x * w0.y + xv.y * w1.y + xv.z * w2.y + xv.w * w3.y;
            acc[r].z += xv.x * w0.z + xv.y * w1.z + xv.z * w2.z + xv.w * w3.z;
            acc[r].w += xv.x * w0.w + xv.y * w1.w + xv.z * w2.w + xv.w * w3.w;
        }
    }
#pragma unroll
    for (int r = 0; r < 8; ++r) {
        int rw = row0 + r * 8 + ty;
        if (rw < n) {
            h4v hv;
            hv.x = (_Float16)acc[r].x; hv.y = (_Float16)acc[r].y;
            hv.z = (_Float16)acc[r].z; hv.w = (_Float16)acc[r].w;
            *reinterpret_cast<h4v*>(&H[(size_t)rw * FOUT + tx * 4]) = hv;
        }
    }
}

// ---- pull agg F=128: g1[v] = relu(sum norm*H[src] + b1), fp16 in / fp32 out
__global__ void k_agg128(const _Float16* __restrict__ H, const uint32_t* __restrict__ rp,
                         const int2* __restrict__ ed, const float* __restrict__ bias,
                         float* __restrict__ out, int n) {
    int wave = (blockIdx.x * blockDim.x + threadIdx.x) >> 6;
    int lane = threadIdx.x & 63;
    if (wave >= n) return;
    const int v = wave;
    int p = (int)rp[v];
    const int e = (int)rp[v + 1];
    const int c0 = lane * 2;

    float ax = 0.f, ay = 0.f;
    for (; p + 1 < e; p += 2) {
        int2 e0 = ed[p], e1 = ed[p + 1];
        h2v h0 = *reinterpret_cast<const h2v*>(&H[(size_t)e0.x * 128 + c0]);
        h2v h1 = *reinterpret_cast<const h2v*>(&H[(size_t)e1.x * 128 + c0]);
        float n0 = __int_as_float(e0.y), n1 = __int_as_float(e1.y);
        ax += n0 * (float)h0.x + n1 * (float)h1.x;
        ay += n0 * (float)h0.y + n1 * (float)h1.y;
    }
    if (p < e) {
        int2 e0 = ed[p];
        h2v h0 = *reinterpret_cast<const h2v*>(&H[(size_t)e0.x * 128 + c0]);
        float n0 = __int_as_float(e0.y);
        ax += n0 * (float)h0.x;
        ay += n0 * (float)h0.y;
    }
    ax = fmaxf(ax + bias[c0], 0.f);
    ay = fmaxf(ay + bias[c0 + 1], 0.f);
    *reinterpret_cast<float2*>(&out[(size_t)v * 128 + c0]) = make_float2(ax, ay);
}

// ---- pull agg F=64: two 32-lane halves alternate edges, shfl-combine ----
__global__ void k_agg64(const _Float16* __restrict__ H, const uint32_t* __restrict__ rp,
                        const int2* __restrict__ ed, const float* __restrict__ bias,
                        float* __restrict__ out, int n) {
    int wave = (blockIdx.x * blockDim.x + threadIdx.x) >> 6;
    int lane = threadIdx.x & 63;
    if (wave >= n) return;
    const int v = wave;
    const int half = lane >> 5;
    const int c0 = (lane & 31) * 2;
    int p = (int)rp[v] + half;
    const int e = (int)rp[v + 1];

    float ax = 0.f, ay = 0.f;
    for (; p < e; p += 2) {
        int2 e0 = ed[p];
        h2v h0 = *reinterpret_cast<const h2v*>(&H[(size_t)e0.x * 64 + c0]);
        float n0 = __int_as_float(e0.y);
        ax += n0 * (float)h0.x;
        ay += n0 * (float)h0.y;
    }
    ax += __shfl_xor(ax, 32);
    ay += __shfl_xor(ay, 32);
    if (lane < 32) {
        ax += bias[c0]; ay += bias[c0 + 1];
        *reinterpret_cast<float2*>(&out[(size_t)v * 64 + c0]) = make_float2(ax, ay);
    }
}

extern "C" void kernel_launch(void* const* d_in, const int* in_sizes, int n_in,
                              void* d_out, int out_size, void* d_ws, size_t ws_size,
                              hipStream_t stream) {
    const float* x  = (const float*)d_in[0];
    const int*   ei = (const int*)d_in[1];
    const float* W1 = (const float*)d_in[2];
    const float* b1 = (const float*)d_in[3];
    const float* W2 = (const float*)d_in[4];
    const float* b2 = (const float*)d_in[5];
    float* out = (float*)d_out;

    const int hidden = in_sizes[3];                 // 128
    const int fin    = in_sizes[2] / hidden;        // 128
    const int n      = in_sizes[0] / fin;           // 50000
    const int E      = in_sizes[1] / 2;             // 800000
    const int M      = E + n;
    const int* rowi = ei;                           // edge_index[0] = sources
    const int* coli = ei + E;                       // edge_index[1] = targets
    (void)n_in; (void)out_size; (void)ws_size;

    char* ws = (char*)d_ws;
    size_t off = 0;
    auto alloc = [&](size_t bytes) -> void* {
        off = (off + 255) & ~(size_t)255;
        void* p = ws + off;
        off += bytes;
        return p;
    };
    uint32_t*  cnt  = (uint32_t*) alloc((size_t)n * 4);
    uint32_t*  fill = (uint32_t*) alloc((size_t)n * 4);
    uint32_t*  rp   = (uint32_t*) alloc((size_t)(n + 1) * 4);
    uint32_t*  part = (uint32_t*) alloc(1024);
    int2*      ed   = (int2*)     alloc((size_t)M * 8);
    _Float16*  h1   = (_Float16*) alloc((size_t)n * 128 * 2);  // reused as h2
    float*     g1   = (float*)    alloc((size_t)n * 128 * 4);
    _Float16*  h2   = h1;

    const int nb256 = (n + 255) / 256;
    const int nbs   = (n + SCAN_CH - 1) / SCAN_CH;   // 98 (<=256 required)

    k_init <<<nb256, 256, 0, stream>>>(cnt, fill, n);
    k_count<<<(E + 255) / 256, 256, 0, stream>>>(coli, cnt, E);
    k_scan_partial<<<nbs, 256, 0, stream>>>(cnt, part, n);
    k_scan_top    <<<1, 256, 0, stream>>>(part, rp + n, nbs);
    k_scan_final  <<<nbs, SCAN_CH, 0, stream>>>(cnt, part, rp, n);
    k_scatter<<<(M + 255) / 256, 256, 0, stream>>>(rowi, coli, cnt, rp, fill, ed, E, n);

    const int gb = (n + 63) / 64;
    k_gemm<128><<<gb, dim3(32, 8), 0, stream>>>(x, W1, h1, n);
    k_agg128<<<(n + 3) / 4, 256, 0, stream>>>(h1, rp, ed, b1, g1, n);
    k_gemm<64><<<gb, dim3(16, 8), 0, stream>>>(g1, W2, h2, n);
    k_agg64 <<<(n + 3) / 4, 256, 0, stream>>>(h2, rp, ed, b2, out, n);
}

// Round 3
// 297.685 us; speedup vs baseline: 1.2491x; 1.1296x over previous
//
#include <hip/hip_runtime.h>
#include <stdint.h>

// ---------------------------------------------------------------------------
// GCN 2-layer encoder, dest-CSR pull aggregation, fp16 intermediates.
//   h1 = fp16(x @ W1) ; g1 = fp16(relu(Agg(h1) + b1))
//   h2 = fp16(g1 @ W2); out = Agg(h2) + b2   [fp32]
// Agg kernels are latency-bound -> deep unroll for memory-level parallelism.
// ---------------------------------------------------------------------------

typedef _Float16 h2v __attribute__((ext_vector_type(2)));
typedef _Float16 h4v __attribute__((ext_vector_type(4)));

__device__ inline int2 ldnt_edge(const int2* p) {
    long long v = __builtin_nontemporal_load(reinterpret_cast<const long long*>(p));
    int2 r; r.x = (int)(uint32_t)(v & 0xffffffffLL); r.y = (int)(v >> 32); return r;
}

__global__ void k_init(uint32_t* __restrict__ cnt, int n) {
    int i = blockIdx.x * blockDim.x + threadIdx.x;
    if (i < n) cnt[i] = 1u;   // self loop
}

__global__ void k_count(const int* __restrict__ col, uint32_t* __restrict__ cnt, int E) {
    int i = blockIdx.x * blockDim.x + threadIdx.x;
    if (i < E) atomicAdd(&cnt[__builtin_nontemporal_load(&col[i])], 1u);
}

// ---- exclusive scan of cnt -> rp (row_ptr); fill preloaded with rp ----
constexpr int SCAN_CH = 512;

__global__ void k_scan_partial(const uint32_t* __restrict__ cnt, uint32_t* __restrict__ part, int n) {
    __shared__ uint32_t s[256];
    int t = threadIdx.x;
    int base = blockIdx.x * SCAN_CH;
    uint32_t v = 0;
    if (base + t       < n) v += cnt[base + t];
    if (base + t + 256 < n) v += cnt[base + t + 256];
    s[t] = v; __syncthreads();
    for (int off = 128; off > 0; off >>= 1) {
        if (t < off) s[t] += s[t + off];
        __syncthreads();
    }
    if (t == 0) part[blockIdx.x] = s[0];
}

__global__ void k_scan_top(uint32_t* __restrict__ part, uint32_t* __restrict__ total_out, int nb) {
    __shared__ uint32_t s[256];
    int t = threadIdx.x;
    uint32_t v = (t < nb) ? part[t] : 0u;
    s[t] = v; __syncthreads();
    for (int off = 1; off < 256; off <<= 1) {
        uint32_t u = (t >= off) ? s[t - off] : 0u;
        __syncthreads();
        s[t] += u;
        __syncthreads();
    }
    if (t < nb) part[t] = s[t] - v;          // exclusive
    if (t == nb - 1) *total_out = s[t];      // rp[n] = E + n
}

__global__ void k_scan_final(const uint32_t* __restrict__ cnt, const uint32_t* __restrict__ part,
                             uint32_t* __restrict__ rp, uint32_t* __restrict__ fill, int n) {
    __shared__ uint32_t s[SCAN_CH];
    int t = threadIdx.x;
    int i = blockIdx.x * SCAN_CH + t;
    uint32_t v = (i < n) ? cnt[i] : 0u;
    s[t] = v; __syncthreads();
    for (int off = 1; off < SCAN_CH; off <<= 1) {
        uint32_t u = (t >= off) ? s[t - off] : 0u;
        __syncthreads();
        s[t] += u;
        __syncthreads();
    }
    if (i < n) {
        uint32_t ex = part[blockIdx.x] + s[t] - v;   // exclusive
        rp[i] = ex;
        fill[i] = ex;                                 // scatter cursor starts at rp
    }
}

// bucket-scatter edges (+ self loops) into dest-CSR order; interleaved {src, norm}
__global__ void k_scatter(const int* __restrict__ row, const int* __restrict__ col,
                          const uint32_t* __restrict__ cnt, uint32_t* __restrict__ fill,
                          int2* __restrict__ ed, int E, int n) {
    int i = blockIdx.x * blockDim.x + threadIdx.x;
    int M = E + n;
    if (i >= M) return;
    int r, c;
    if (i < E) {
        r = __builtin_nontemporal_load(&row[i]);
        c = __builtin_nontemporal_load(&col[i]);
    } else {
        r = c = i - E;
    }
    uint32_t p = atomicAdd(&fill[c], 1u);
    float nrm = rsqrtf((float)cnt[r] * (float)cnt[c]);
    ed[p] = make_int2(r, __float_as_int(nrm));
}

// ---- GEMM: H[n,FOUT](fp16) = X[n,128] @ W[128,FOUT](fp32), W in LDS ----
template <int FOUT, typename XT>
__global__ __launch_bounds__((FOUT / 4) * 8)
void k_gemm(const XT* __restrict__ X, const float* __restrict__ W,
            _Float16* __restrict__ H, int n) {
    constexpr int K = 128;
    __shared__ float Wl[K * FOUT];
    const int tx = threadIdx.x;                 // 0..FOUT/4-1 (col quad)
    const int ty = threadIdx.y;                 // 0..7
    const int nthr = (FOUT / 4) * 8;
    const int tid = ty * (FOUT / 4) + tx;
    for (int i = tid; i < K * FOUT / 4; i += nthr)
        reinterpret_cast<float4*>(Wl)[i] = reinterpret_cast<const float4*>(W)[i];
    __syncthreads();

    const int row0 = blockIdx.x * 64;
    float4 acc[8];
#pragma unroll
    for (int r = 0; r < 8; ++r) acc[r] = make_float4(0.f, 0.f, 0.f, 0.f);

#pragma unroll 2
    for (int k0 = 0; k0 < K; k0 += 4) {
        const float4 w0 = *reinterpret_cast<const float4*>(&Wl[(k0 + 0) * FOUT + tx * 4]);
        const float4 w1 = *reinterpret_cast<const float4*>(&Wl[(k0 + 1) * FOUT + tx * 4]);
        const float4 w2 = *reinterpret_cast<const float4*>(&Wl[(k0 + 2) * FOUT + tx * 4]);
        const float4 w3 = *reinterpret_cast<const float4*>(&Wl[(k0 + 3) * FOUT + tx * 4]);
#pragma unroll
        for (int r = 0; r < 8; ++r) {
            int rw = row0 + r * 8 + ty;
            int rl = rw < n ? rw : n - 1;       // clamp (store is guarded)
            float4 xv;
            if constexpr (sizeof(XT) == 2) {
                h4v t = *reinterpret_cast<const h4v*>(&X[(size_t)rl * K + k0]);
                xv = make_float4((float)t.x, (float)t.y, (float)t.z, (float)t.w);
            } else {
                xv = *reinterpret_cast<const float4*>(&X[(size_t)rl * K + k0]);
            }
            acc[r].x += xv.x * w0.x + xv.y * w1.x + xv.z * w2.x + xv.w * w3.x;
            acc[r].y += xv.x * w0.y + xv.y * w1.y + xv.z * w2.y + xv.w * w3.y;
            acc[r].z += xv.x * w0.z + xv.y * w1.z + xv.z * w2.z + xv.w * w3.z;
            acc[r].w += xv.x * w0.w + xv.y * w1.w + xv.z * w2.w + xv.w * w3.w;
        }
    }
#pragma unroll
    for (int r = 0; r < 8; ++r) {
        int rw = row0 + r * 8 + ty;
        if (rw < n) {
            h4v hv;
            hv.x = (_Float16)acc[r].x; hv.y = (_Float16)acc[r].y;
            hv.z = (_Float16)acc[r].z; hv.w = (_Float16)acc[r].w;
            *reinterpret_cast<h4v*>(&H[(size_t)rw * FOUT + tx * 4]) = hv;
        }
    }
}

// ---- pull agg F=128, unroll-8: g1 = fp16(relu(sum norm*H[src] + b1)) ----
__global__ void k_agg128(const _Float16* __restrict__ H, const uint32_t* __restrict__ rp,
                         const int2* __restrict__ ed, const float* __restrict__ bias,
                         _Float16* __restrict__ out, int n) {
    int wave = (blockIdx.x * blockDim.x + threadIdx.x) >> 6;
    int lane = threadIdx.x & 63;
    if (wave >= n) return;
    const int v = wave;
    int p = (int)rp[v];
    const int e = (int)rp[v + 1];
    const int c0 = lane * 2;

    float ax = 0.f, ay = 0.f;
    // 8 independent gathers in flight
    for (; p + 8 <= e; p += 8) {
        int2 ee[8];
#pragma unroll
        for (int u = 0; u < 8; ++u) ee[u] = ldnt_edge(&ed[p + u]);
        h2v hh[8];
#pragma unroll
        for (int u = 0; u < 8; ++u)
            hh[u] = *reinterpret_cast<const h2v*>(&H[(size_t)ee[u].x * 128 + c0]);
#pragma unroll
        for (int u = 0; u < 8; ++u) {
            float nn = __int_as_float(ee[u].y);
            ax += nn * (float)hh[u].x;
            ay += nn * (float)hh[u].y;
        }
    }
    if (p + 4 <= e) {
        int2 ee[4];
#pragma unroll
        for (int u = 0; u < 4; ++u) ee[u] = ldnt_edge(&ed[p + u]);
        h2v hh[4];
#pragma unroll
        for (int u = 0; u < 4; ++u)
            hh[u] = *reinterpret_cast<const h2v*>(&H[(size_t)ee[u].x * 128 + c0]);
#pragma unroll
        for (int u = 0; u < 4; ++u) {
            float nn = __int_as_float(ee[u].y);
            ax += nn * (float)hh[u].x;
            ay += nn * (float)hh[u].y;
        }
        p += 4;
    }
    for (; p < e; ++p) {
        int2 e0 = ldnt_edge(&ed[p]);
        h2v h0 = *reinterpret_cast<const h2v*>(&H[(size_t)e0.x * 128 + c0]);
        float n0 = __int_as_float(e0.y);
        ax += n0 * (float)h0.x;
        ay += n0 * (float)h0.y;
    }
    ax = fmaxf(ax + bias[c0], 0.f);
    ay = fmaxf(ay + bias[c0 + 1], 0.f);
    h2v o; o.x = (_Float16)ax; o.y = (_Float16)ay;
    *reinterpret_cast<h2v*>(&out[(size_t)v * 128 + c0]) = o;
}

// ---- pull agg F=64: two 32-lane halves, stride-2 edges, unroll-4/half ----
__global__ void k_agg64(const _Float16* __restrict__ H, const uint32_t* __restrict__ rp,
                        const int2* __restrict__ ed, const float* __restrict__ bias,
                        float* __restrict__ out, int n) {
    int wave = (blockIdx.x * blockDim.x + threadIdx.x) >> 6;
    int lane = threadIdx.x & 63;
    if (wave >= n) return;
    const int v = wave;
    const int half = lane >> 5;
    const int c0 = (lane & 31) * 2;
    int p = (int)rp[v] + half;
    const int e = (int)rp[v + 1];

    float ax = 0.f, ay = 0.f;
    for (; p + 6 < e; p += 8) {      // edges p, p+2, p+4, p+6 for this half
        int2 ee[4];
#pragma unroll
        for (int u = 0; u < 4; ++u) ee[u] = ldnt_edge(&ed[p + 2 * u]);
        h2v hh[4];
#pragma unroll
        for (int u = 0; u < 4; ++u)
            hh[u] = *reinterpret_cast<const h2v*>(&H[(size_t)ee[u].x * 64 + c0]);
#pragma unroll
        for (int u = 0; u < 4; ++u) {
            float nn = __int_as_float(ee[u].y);
            ax += nn * (float)hh[u].x;
            ay += nn * (float)hh[u].y;
        }
    }
    for (; p < e; p += 2) {
        int2 e0 = ldnt_edge(&ed[p]);
        h2v h0 = *reinterpret_cast<const h2v*>(&H[(size_t)e0.x * 64 + c0]);
        float n0 = __int_as_float(e0.y);
        ax += n0 * (float)h0.x;
        ay += n0 * (float)h0.y;
    }
    ax += __shfl_xor(ax, 32);
    ay += __shfl_xor(ay, 32);
    if (lane < 32) {
        ax += bias[c0]; ay += bias[c0 + 1];
        *reinterpret_cast<float2*>(&out[(size_t)v * 64 + c0]) = make_float2(ax, ay);
    }
}

extern "C" void kernel_launch(void* const* d_in, const int* in_sizes, int n_in,
                              void* d_out, int out_size, void* d_ws, size_t ws_size,
                              hipStream_t stream) {
    const float* x  = (const float*)d_in[0];
    const int*   ei = (const int*)d_in[1];
    const float* W1 = (const float*)d_in[2];
    const float* b1 = (const float*)d_in[3];
    const float* W2 = (const float*)d_in[4];
    const float* b2 = (const float*)d_in[5];
    float* out = (float*)d_out;

    const int hidden = in_sizes[3];                 // 128
    const int fin    = in_sizes[2] / hidden;        // 128
    const int n      = in_sizes[0] / fin;           // 50000
    const int E      = in_sizes[1] / 2;             // 800000
    const int M      = E + n;
    const int* rowi = ei;                           // edge_index[0] = sources
    const int* coli = ei + E;                       // edge_index[1] = targets
    (void)n_in; (void)out_size; (void)ws_size;

    char* ws = (char*)d_ws;
    size_t off = 0;
    auto alloc = [&](size_t bytes) -> void* {
        off = (off + 255) & ~(size_t)255;
        void* p = ws + off;
        off += bytes;
        return p;
    };
    uint32_t*  cnt  = (uint32_t*) alloc((size_t)n * 4);
    uint32_t*  fill = (uint32_t*) alloc((size_t)n * 4);
    uint32_t*  rp   = (uint32_t*) alloc((size_t)(n + 1) * 4);
    uint32_t*  part = (uint32_t*) alloc(1024);
    int2*      ed   = (int2*)     alloc((size_t)M * 8);
    _Float16*  h1   = (_Float16*) alloc((size_t)n * 128 * 2);  // reused as h2
    _Float16*  g1   = (_Float16*) alloc((size_t)n * 128 * 2);
    _Float16*  h2   = h1;

    const int nb256 = (n + 255) / 256;
    const int nbs   = (n + SCAN_CH - 1) / SCAN_CH;   // 98 (<=256 required)

    k_init <<<nb256, 256, 0, stream>>>(cnt, n);
    k_count<<<(E + 255) / 256, 256, 0, stream>>>(coli, cnt, E);
    k_scan_partial<<<nbs, 256, 0, stream>>>(cnt, part, n);
    k_scan_top    <<<1, 256, 0, stream>>>(part, rp + n, nbs);
    k_scan_final  <<<nbs, SCAN_CH, 0, stream>>>(cnt, part, rp, fill, n);
    k_scatter<<<(M + 255) / 256, 256, 0, stream>>>(rowi, coli, cnt, fill, ed, E, n);

    const int gb = (n + 63) / 64;
    k_gemm<128, float>   <<<gb, dim3(32, 8), 0, stream>>>(x, W1, h1, n);
    k_agg128<<<(n + 3) / 4, 256, 0, stream>>>(h1, rp, ed, b1, g1, n);
    k_gemm<64, _Float16> <<<gb, dim3(16, 8), 0, stream>>>(g1, W2, h2, n);
    k_agg64 <<<(n + 3) / 4, 256, 0, stream>>>(h2, rp, ed, b2, out, n);
}

// Round 4
// 254.634 us; speedup vs baseline: 1.4603x; 1.1691x over previous
//
#include <hip/hip_runtime.h>
#include <stdint.h>

// ---------------------------------------------------------------------------
// GCN 2-layer encoder, dest-CSR pull aggregation, fp16 intermediates,
// MFMA (16x16x32 f16) GEMMs.
//   h1 = fp16(x @ W1) ; g1 = fp16(relu(Agg(h1) + b1))
//   h2 = fp16(g1 @ W2); out = Agg(h2) + b2   [fp32]
// ---------------------------------------------------------------------------

typedef _Float16 h2v  __attribute__((ext_vector_type(2)));
typedef _Float16 h4v  __attribute__((ext_vector_type(4)));
typedef _Float16 f16x8 __attribute__((ext_vector_type(8)));
typedef float    f32x4 __attribute__((ext_vector_type(4)));

__device__ inline int2 ldnt_edge(const int2* p) {
    long long v = __builtin_nontemporal_load(reinterpret_cast<const long long*>(p));
    int2 r; r.x = (int)(uint32_t)(v & 0xffffffffLL); r.y = (int)(v >> 32); return r;
}

__global__ void k_init(uint32_t* __restrict__ cnt, int n) {
    int i = blockIdx.x * blockDim.x + threadIdx.x;
    if (i < n) cnt[i] = 1u;   // self loop
}

__global__ void k_count(const int* __restrict__ col, uint32_t* __restrict__ cnt, int E) {
    int i = blockIdx.x * blockDim.x + threadIdx.x;
    if (i < E) atomicAdd(&cnt[__builtin_nontemporal_load(&col[i])], 1u);
}

// convert W1 [128][128] and W2 [128][64] (both fp32, K-major) to fp16
// transposed layouts WT1 [128][128], WT2 [64][128]  (rows = out-feature)
__global__ void k_wprep(const float* __restrict__ W1, const float* __restrict__ W2,
                        _Float16* __restrict__ WT1, _Float16* __restrict__ WT2) {
    int i = blockIdx.x * blockDim.x + threadIdx.x;
    if (i < 128 * 128) {
        int f = i >> 7, k = i & 127;
        WT1[i] = (_Float16)W1[k * 128 + f];
    }
    int j = i - 128 * 128;
    if (j >= 0 && j < 64 * 128) {
        int f = j >> 7, k = j & 127;
        WT2[j] = (_Float16)W2[k * 64 + f];
    }
}

// ---- exclusive scan of cnt -> rp (row_ptr); fill preloaded with rp ----
constexpr int SCAN_CH = 512;

__global__ void k_scan_partial(const uint32_t* __restrict__ cnt, uint32_t* __restrict__ part, int n) {
    __shared__ uint32_t s[256];
    int t = threadIdx.x;
    int base = blockIdx.x * SCAN_CH;
    uint32_t v = 0;
    if (base + t       < n) v += cnt[base + t];
    if (base + t + 256 < n) v += cnt[base + t + 256];
    s[t] = v; __syncthreads();
    for (int off = 128; off > 0; off >>= 1) {
        if (t < off) s[t] += s[t + off];
        __syncthreads();
    }
    if (t == 0) part[blockIdx.x] = s[0];
}

__global__ void k_scan_top(uint32_t* __restrict__ part, uint32_t* __restrict__ total_out, int nb) {
    __shared__ uint32_t s[256];
    int t = threadIdx.x;
    uint32_t v = (t < nb) ? part[t] : 0u;
    s[t] = v; __syncthreads();
    for (int off = 1; off < 256; off <<= 1) {
        uint32_t u = (t >= off) ? s[t - off] : 0u;
        __syncthreads();
        s[t] += u;
        __syncthreads();
    }
    if (t < nb) part[t] = s[t] - v;          // exclusive
    if (t == nb - 1) *total_out = s[t];      // rp[n] = E + n
}

__global__ void k_scan_final(const uint32_t* __restrict__ cnt, const uint32_t* __restrict__ part,
                             uint32_t* __restrict__ rp, uint32_t* __restrict__ fill, int n) {
    __shared__ uint32_t s[SCAN_CH];
    int t = threadIdx.x;
    int i = blockIdx.x * SCAN_CH + t;
    uint32_t v = (i < n) ? cnt[i] : 0u;
    s[t] = v; __syncthreads();
    for (int off = 1; off < SCAN_CH; off <<= 1) {
        uint32_t u = (t >= off) ? s[t - off] : 0u;
        __syncthreads();
        s[t] += u;
        __syncthreads();
    }
    if (i < n) {
        uint32_t ex = part[blockIdx.x] + s[t] - v;   // exclusive
        rp[i] = ex;
        fill[i] = ex;                                 // scatter cursor starts at rp
    }
}

// bucket-scatter edges (+ self loops) into dest-CSR order; interleaved {src, norm}
__global__ void k_scatter(const int* __restrict__ row, const int* __restrict__ col,
                          const uint32_t* __restrict__ cnt, uint32_t* __restrict__ fill,
                          int2* __restrict__ ed, int E, int n) {
    int i = blockIdx.x * blockDim.x + threadIdx.x;
    int M = E + n;
    if (i >= M) return;
    int r, c;
    if (i < E) {
        r = __builtin_nontemporal_load(&row[i]);
        c = __builtin_nontemporal_load(&col[i]);
    } else {
        r = c = i - E;
    }
    uint32_t p = atomicAdd(&fill[c], 1u);
    float nrm = rsqrtf((float)cnt[r] * (float)cnt[c]);
    ed[p] = make_int2(r, __float_as_int(nrm));
}

// ---- MFMA GEMM: H[n,FOUT](fp16) = X[n,128] @ W[128,FOUT]
// WT = [FOUT][128] fp16 (transposed W). Computes C[feat][node] tiles:
//   A-frag = WT rows (feats), B-frag = X rows (nodes), K=128 in 4 steps.
// Per block: 4 waves x 16 nodes = 64 nodes; each wave does FOUT/16 feat tiles.
template <int FOUT, typename XT>
__global__ __launch_bounds__(256)
void k_gemm_mfma(const XT* __restrict__ X, const _Float16* __restrict__ WT,
                 _Float16* __restrict__ H, int n) {
    constexpr int K  = 128;
    constexpr int KP = K + 8;           // +16B pad -> conflict-free ds_read_b128
    constexpr int NT = FOUT / 16;
    __shared__ _Float16 Wl[FOUT * KP];

    const int tid = threadIdx.x;
    for (int i = tid; i < FOUT * (K / 8); i += 256) {
        int f = i / (K / 8), kc = i % (K / 8);
        *reinterpret_cast<f16x8*>(&Wl[f * KP + kc * 8]) =
            *reinterpret_cast<const f16x8*>(&WT[f * K + kc * 8]);
    }
    __syncthreads();

    const int wid  = tid >> 6;
    const int lane = tid & 63;
    const int col  = lane & 15;         // node within 16-tile (B col / C col)
    const int krow = lane >> 4;         // k-chunk selector (0..3)
    const int node = blockIdx.x * 64 + wid * 16 + col;
    const int nld  = node < n ? node : n - 1;

    f32x4 acc[NT];
#pragma unroll
    for (int t = 0; t < NT; ++t) acc[t] = (f32x4){0.f, 0.f, 0.f, 0.f};

#pragma unroll
    for (int ks = 0; ks < 4; ++ks) {
        const int k0 = ks * 32 + krow * 8;
        f16x8 b;
        if constexpr (sizeof(XT) == 4) {
            float4 x0 = *reinterpret_cast<const float4*>(&X[(size_t)nld * K + k0]);
            float4 x1 = *reinterpret_cast<const float4*>(&X[(size_t)nld * K + k0 + 4]);
            b[0] = (_Float16)x0.x; b[1] = (_Float16)x0.y;
            b[2] = (_Float16)x0.z; b[3] = (_Float16)x0.w;
            b[4] = (_Float16)x1.x; b[5] = (_Float16)x1.y;
            b[6] = (_Float16)x1.z; b[7] = (_Float16)x1.w;
        } else {
            b = *reinterpret_cast<const f16x8*>(&X[(size_t)nld * K + k0]);
        }
#pragma unroll
        for (int t = 0; t < NT; ++t) {
            f16x8 a = *reinterpret_cast<const f16x8*>(&Wl[(t * 16 + col) * KP + k0]);
            acc[t] = __builtin_amdgcn_mfma_f32_16x16x32_f16(a, b, acc[t], 0, 0, 0);
        }
    }

    // C layout: col = lane&15 (node), row = krow*4 + j (feat within tile)
    if (node < n) {
#pragma unroll
        for (int t = 0; t < NT; ++t) {
            h4v hv;
            hv.x = (_Float16)acc[t][0];
            hv.y = (_Float16)acc[t][1];
            hv.z = (_Float16)acc[t][2];
            hv.w = (_Float16)acc[t][3];
            *reinterpret_cast<h4v*>(&H[(size_t)node * FOUT + t * 16 + krow * 4]) = hv;
        }
    }
}

// ---- pull agg F=128, unroll-8: g1 = fp16(relu(sum norm*H[src] + b1)) ----
__global__ void k_agg128(const _Float16* __restrict__ H, const uint32_t* __restrict__ rp,
                         const int2* __restrict__ ed, const float* __restrict__ bias,
                         _Float16* __restrict__ out, int n) {
    int wave = (blockIdx.x * blockDim.x + threadIdx.x) >> 6;
    int lane = threadIdx.x & 63;
    if (wave >= n) return;
    const int v = wave;
    int p = (int)rp[v];
    const int e = (int)rp[v + 1];
    const int c0 = lane * 2;

    float ax = 0.f, ay = 0.f;
    for (; p + 8 <= e; p += 8) {
        int2 ee[8];
#pragma unroll
        for (int u = 0; u < 8; ++u) ee[u] = ldnt_edge(&ed[p + u]);
        h2v hh[8];
#pragma unroll
        for (int u = 0; u < 8; ++u)
            hh[u] = *reinterpret_cast<const h2v*>(&H[(size_t)ee[u].x * 128 + c0]);
#pragma unroll
        for (int u = 0; u < 8; ++u) {
            float nn = __int_as_float(ee[u].y);
            ax += nn * (float)hh[u].x;
            ay += nn * (float)hh[u].y;
        }
    }
    if (p + 4 <= e) {
        int2 ee[4];
#pragma unroll
        for (int u = 0; u < 4; ++u) ee[u] = ldnt_edge(&ed[p + u]);
        h2v hh[4];
#pragma unroll
        for (int u = 0; u < 4; ++u)
            hh[u] = *reinterpret_cast<const h2v*>(&H[(size_t)ee[u].x * 128 + c0]);
#pragma unroll
        for (int u = 0; u < 4; ++u) {
            float nn = __int_as_float(ee[u].y);
            ax += nn * (float)hh[u].x;
            ay += nn * (float)hh[u].y;
        }
        p += 4;
    }
    for (; p < e; ++p) {
        int2 e0 = ldnt_edge(&ed[p]);
        h2v h0 = *reinterpret_cast<const h2v*>(&H[(size_t)e0.x * 128 + c0]);
        float n0 = __int_as_float(e0.y);
        ax += n0 * (float)h0.x;
        ay += n0 * (float)h0.y;
    }
    ax = fmaxf(ax + bias[c0], 0.f);
    ay = fmaxf(ay + bias[c0 + 1], 0.f);
    h2v o; o.x = (_Float16)ax; o.y = (_Float16)ay;
    *reinterpret_cast<h2v*>(&out[(size_t)v * 128 + c0]) = o;
}

// ---- pull agg F=64: two 32-lane halves, stride-2 edges, unroll-4/half ----
__global__ void k_agg64(const _Float16* __restrict__ H, const uint32_t* __restrict__ rp,
                        const int2* __restrict__ ed, const float* __restrict__ bias,
                        float* __restrict__ out, int n) {
    int wave = (blockIdx.x * blockDim.x + threadIdx.x) >> 6;
    int lane = threadIdx.x & 63;
    if (wave >= n) return;
    const int v = wave;
    const int half = lane >> 5;
    const int c0 = (lane & 31) * 2;
    int p = (int)rp[v] + half;
    const int e = (int)rp[v + 1];

    float ax = 0.f, ay = 0.f;
    for (; p + 6 < e; p += 8) {      // edges p, p+2, p+4, p+6 for this half
        int2 ee[4];
#pragma unroll
        for (int u = 0; u < 4; ++u) ee[u] = ldnt_edge(&ed[p + 2 * u]);
        h2v hh[4];
#pragma unroll
        for (int u = 0; u < 4; ++u)
            hh[u] = *reinterpret_cast<const h2v*>(&H[(size_t)ee[u].x * 64 + c0]);
#pragma unroll
        for (int u = 0; u < 4; ++u) {
            float nn = __int_as_float(ee[u].y);
            ax += nn * (float)hh[u].x;
            ay += nn * (float)hh[u].y;
        }
    }
    for (; p < e; p += 2) {
        int2 e0 = ldnt_edge(&ed[p]);
        h2v h0 = *reinterpret_cast<const h2v*>(&H[(size_t)e0.x * 64 + c0]);
        float n0 = __int_as_float(e0.y);
        ax += n0 * (float)h0.x;
        ay += n0 * (float)h0.y;
    }
    ax += __shfl_xor(ax, 32);
    ay += __shfl_xor(ay, 32);
    if (lane < 32) {
        ax += bias[c0]; ay += bias[c0 + 1];
        *reinterpret_cast<float2*>(&out[(size_t)v * 64 + c0]) = make_float2(ax, ay);
    }
}

extern "C" void kernel_launch(void* const* d_in, const int* in_sizes, int n_in,
                              void* d_out, int out_size, void* d_ws, size_t ws_size,
                              hipStream_t stream) {
    const float* x  = (const float*)d_in[0];
    const int*   ei = (const int*)d_in[1];
    const float* W1 = (const float*)d_in[2];
    const float* b1 = (const float*)d_in[3];
    const float* W2 = (const float*)d_in[4];
    const float* b2 = (const float*)d_in[5];
    float* out = (float*)d_out;

    const int hidden = in_sizes[3];                 // 128
    const int fin    = in_sizes[2] / hidden;        // 128
    const int n      = in_sizes[0] / fin;           // 50000
    const int E      = in_sizes[1] / 2;             // 800000
    const int M      = E + n;
    const int* rowi = ei;                           // edge_index[0] = sources
    const int* coli = ei + E;                       // edge_index[1] = targets
    (void)n_in; (void)out_size; (void)ws_size;

    char* ws = (char*)d_ws;
    size_t off = 0;
    auto alloc = [&](size_t bytes) -> void* {
        off = (off + 255) & ~(size_t)255;
        void* p = ws + off;
        off += bytes;
        return p;
    };
    uint32_t*  cnt  = (uint32_t*) alloc((size_t)n * 4);
    uint32_t*  fill = (uint32_t*) alloc((size_t)n * 4);
    uint32_t*  rp   = (uint32_t*) alloc((size_t)(n + 1) * 4);
    uint32_t*  part = (uint32_t*) alloc(1024);
    int2*      ed   = (int2*)     alloc((size_t)M * 8);
    _Float16*  h1   = (_Float16*) alloc((size_t)n * 128 * 2);  // reused as h2
    _Float16*  g1   = (_Float16*) alloc((size_t)n * 128 * 2);
    _Float16*  WT1  = (_Float16*) alloc(128 * 128 * 2);
    _Float16*  WT2  = (_Float16*) alloc(64 * 128 * 2);
    _Float16*  h2   = h1;

    const int nb256 = (n + 255) / 256;
    const int nbs   = (n + SCAN_CH - 1) / SCAN_CH;   // 98 (<=256 required)

    k_wprep<<<96, 256, 0, stream>>>(W1, W2, WT1, WT2);
    k_init <<<nb256, 256, 0, stream>>>(cnt, n);
    k_count<<<(E + 255) / 256, 256, 0, stream>>>(coli, cnt, E);
    k_scan_partial<<<nbs, 256, 0, stream>>>(cnt, part, n);
    k_scan_top    <<<1, 256, 0, stream>>>(part, rp + n, nbs);
    k_scan_final  <<<nbs, SCAN_CH, 0, stream>>>(cnt, part, rp, fill, n);
    k_scatter<<<(M + 255) / 256, 256, 0, stream>>>(rowi, coli, cnt, fill, ed, E, n);

    const int gb = (n + 63) / 64;
    k_gemm_mfma<128, float>   <<<gb, 256, 0, stream>>>(x, WT1, h1, n);
    k_agg128<<<(n + 3) / 4, 256, 0, stream>>>(h1, rp, ed, b1, g1, n);
    k_gemm_mfma<64, _Float16> <<<gb, 256, 0, stream>>>(g1, WT2, h2, n);
    k_agg64 <<<(n + 3) / 4, 256, 0, stream>>>(h2, rp, ed, b2, out, n);
}